// Round 2
// baseline (491.627 us; speedup 1.0000x reference)
//
#include <hip/hip_runtime.h>
#include <hip/hip_bf16.h>

// Problem constants
#define B_    2
#define S_    2048
#define E_    2048
#define H_    16
#define HKV_  4
#define D_    128
#define QKV_  3072   // D*(H+2*HKV)

#define LOG2E  1.4426950408889634f
#define SCALE  0.08838834764831845f   // 1/sqrt(128)

typedef __attribute__((ext_vector_type(8))) short short8;   // 8 x bf16 (4 VGPRs)
typedef __attribute__((ext_vector_type(4))) float floatx4;  // MFMA 16x16 accumulator

__device__ __forceinline__ float b2f(unsigned short u) {
    union { unsigned int i; float f; } v; v.i = ((unsigned int)u) << 16; return v.f;
}
__device__ __forceinline__ unsigned short f2b(float f) {
    union { float f; unsigned int i; } v; v.f = f;
    unsigned int r = v.i + 0x7FFFu + ((v.i >> 16) & 1u);  // round-to-nearest-even
    return (unsigned short)(r >> 16);
}

// ---------------------------------------------------------------------------
// f32 -> bf16 convert (contiguous). 4 elems/thread.
// ---------------------------------------------------------------------------
__global__ __launch_bounds__(256) void cvt_f32_bf16(
    const float* __restrict__ src, unsigned short* __restrict__ dst, int n)
{
    int i = (blockIdx.x * 256 + threadIdx.x) * 4;
    if (i + 3 < n) {
        float4 v = *(const float4*)&src[i];
        ushort4 o;
        o.x = f2b(v.x); o.y = f2b(v.y); o.z = f2b(v.z); o.w = f2b(v.w);
        *(ushort4*)&dst[i] = o;
    }
}

// ---------------------------------------------------------------------------
// f32 -> bf16 transpose: src[R][C] f32 -> dst[C][R] bf16. block (32,8).
// ---------------------------------------------------------------------------
__global__ __launch_bounds__(256) void transpose_f32_bf16(
    const float* __restrict__ src, unsigned short* __restrict__ dst,
    int R, int C)
{
    __shared__ unsigned short tile[32][33];
    const int c0 = blockIdx.x * 32, r0 = blockIdx.y * 32;
    const int tx = threadIdx.x, ty = threadIdx.y;
    #pragma unroll
    for (int i = 0; i < 4; i++)
        tile[ty + 8 * i][tx] = f2b(src[(size_t)(r0 + ty + 8 * i) * C + c0 + tx]);
    __syncthreads();
    #pragma unroll
    for (int i = 0; i < 4; i++)
        dst[(size_t)(c0 + ty + 8 * i) * R + r0 + tx] = tile[tx][ty + 8 * i];
}

// ---------------------------------------------------------------------------
// bf16 -> bf16 batched transpose (for V): src[batch][R][C] -> dst[batch][C][R]
// ---------------------------------------------------------------------------
__global__ __launch_bounds__(256) void transpose_bf16(
    const unsigned short* __restrict__ src, unsigned short* __restrict__ dst,
    int R, int C)
{
    __shared__ unsigned short tile[32][33];
    const size_t boff = (size_t)blockIdx.z * R * C;
    src += boff; dst += boff;
    const int c0 = blockIdx.x * 32, r0 = blockIdx.y * 32;
    const int tx = threadIdx.x, ty = threadIdx.y;
    #pragma unroll
    for (int i = 0; i < 4; i++)
        tile[ty + 8 * i][tx] = src[(size_t)(r0 + ty + 8 * i) * C + c0 + tx];
    __syncthreads();
    #pragma unroll
    for (int i = 0; i < 4; i++)
        dst[(size_t)(c0 + ty + 8 * i) * R + r0 + tx] = tile[tx][ty + 8 * i];
}

// ---------------------------------------------------------------------------
// bf16 MFMA GEMM, B transposed: C[M][N] = A[M][K] @ Bt[N][K]^T + bias[N]
// 128x128 tile per 256-thread block, BK=64, 4 waves each computing 64x64.
// OUTF32: 1 -> write float, 0 -> write bf16.
// ---------------------------------------------------------------------------
template<int OUTF32>
__global__ __launch_bounds__(256) void gemm_bt(
    const unsigned short* __restrict__ A, const unsigned short* __restrict__ Bt,
    const float* __restrict__ bias, void* __restrict__ Cv,
    int M, int N, int K)
{
    __shared__ unsigned short As[128][72];
    __shared__ unsigned short Bs[128][72];
    const int tid = threadIdx.x;
    const int m0 = blockIdx.y * 128, n0 = blockIdx.x * 128;
    const int wave = tid >> 6, lane = tid & 63, ln = lane & 15, kq = lane >> 4;
    const int wm = (wave >> 1) * 64, wn = (wave & 1) * 64;

    floatx4 acc[4][4];
    #pragma unroll
    for (int i = 0; i < 4; i++)
        #pragma unroll
        for (int j = 0; j < 4; j++) {
            acc[i][j][0] = 0.f; acc[i][j][1] = 0.f; acc[i][j][2] = 0.f; acc[i][j][3] = 0.f;
        }

    const int srow = tid >> 3;            // 0..31
    const int scol = (tid & 7) * 8;       // elem offset in k

    for (int k0 = 0; k0 < K; k0 += 64) {
        __syncthreads();
        #pragma unroll
        for (int i = 0; i < 4; i++) {
            int row = srow + i * 32;
            *(uint4*)&As[row][scol] = *(const uint4*)&A [(size_t)(m0 + row) * K + k0 + scol];
            *(uint4*)&Bs[row][scol] = *(const uint4*)&Bt[(size_t)(n0 + row) * K + k0 + scol];
        }
        __syncthreads();
        #pragma unroll
        for (int ks = 0; ks < 2; ks++) {
            short8 af[4], bg[4];
            #pragma unroll
            for (int i = 0; i < 4; i++)
                af[i] = *(const short8*)&As[wm + i * 16 + ln][ks * 32 + kq * 8];
            #pragma unroll
            for (int j = 0; j < 4; j++)
                bg[j] = *(const short8*)&Bs[wn + j * 16 + ln][ks * 32 + kq * 8];
            #pragma unroll
            for (int i = 0; i < 4; i++)
                #pragma unroll
                for (int j = 0; j < 4; j++)
                    acc[i][j] = __builtin_amdgcn_mfma_f32_16x16x32_bf16(af[i], bg[j], acc[i][j], 0, 0, 0);
        }
    }

    #pragma unroll
    for (int j = 0; j < 4; j++) {
        int col = n0 + wn + j * 16 + ln;
        float bv = bias[col];
        #pragma unroll
        for (int i = 0; i < 4; i++) {
            int rowb = m0 + wm + i * 16 + kq * 4;
            #pragma unroll
            for (int r = 0; r < 4; r++) {
                float val = acc[i][j][r] + bv;
                if (OUTF32) ((float*)Cv)[(size_t)(rowb + r) * N + col] = val;
                else ((unsigned short*)Cv)[(size_t)(rowb + r) * N + col] = f2b(val);
            }
        }
    }
}

// ---------------------------------------------------------------------------
// Fused depthwise causal conv (DCONV=4) + RoPE + q/k/v split-scatter.
// One block per (b,s); 1792 items = 1024 q-pairs + 256 k-pairs + 512 v elems.
// ---------------------------------------------------------------------------
__device__ __forceinline__ float conv_at(
    const unsigned short* __restrict__ qb, const float* __restrict__ cw,
    const float* __restrict__ cb, int s, int c)
{
    float acc = cb[c];
    const float* w = cw + c * 4;
    #pragma unroll
    for (int t = 0; t < 4; t++) {
        int sp = s - 3 + t;
        if (sp >= 0) acc += b2f(qb[(size_t)sp * QKV_ + c]) * w[t];
    }
    return acc;
}

__global__ __launch_bounds__(256) void conv_rot(
    const unsigned short* __restrict__ qkv, const float* __restrict__ cw,
    const float* __restrict__ cb, unsigned short* __restrict__ qo,
    unsigned short* __restrict__ ko, unsigned short* __restrict__ vo)
{
    const int bs = blockIdx.x;
    const int b = bs >> 11, s = bs & 2047;
    const unsigned short* qb = qkv + (size_t)b * S_ * QKV_;

    for (int it = threadIdx.x; it < 1792; it += 256) {
        if (it < 1280) {
            const int isq = it < 1024;
            const int rel = isq ? it : it - 1024;
            const int head = rel >> 6, d = rel & 63;
            const int c1 = (isq ? head * 128 : 2048 + head * 128) + d;
            float x1 = conv_at(qb, cw, cb, s, c1);
            float x2 = conv_at(qb, cw, cb, s, c1 + 64);
            // inv_freq = 10000^(-d/64) = 2^(-d*log2(10000)/64)
            float inv = exp2f((float)d * -0.2076205059304601f);
            float ang = (float)s * inv;
            float sn, cs;
            sincosf(ang, &sn, &cs);
            float r1 = x1 * cs - x2 * sn;
            float r2 = x2 * cs + x1 * sn;
            unsigned short* dst = isq
                ? qo + ((size_t)(b * H_   + head) * S_ + s) * D_
                : ko + ((size_t)(b * HKV_ + head) * S_ + s) * D_;
            dst[d]      = f2b(r1);
            dst[d + 64] = f2b(r2);
        } else {
            const int idx = it - 1280;          // 0..511
            const int g = idx >> 7, d = idx & 127;
            float vv = conv_at(qb, cw, cb, s, 2560 + idx);
            vo[((size_t)(b * HKV_ + g) * S_ + s) * D_ + d] = f2b(vv);
        }
    }
}

// ---------------------------------------------------------------------------
// Flash attention (causal, GQA rep=4). Block = (qt, h, b); 4 waves; each wave
// owns 16 q-rows of a 64-row Q tile. K-tiles/V-tiles of 64 kv positions.
// V pre-transposed (vT[b][g][d][s]) -> coalesced staging + k-contiguous PV
// B-fragments. P round-trips through LDS (C-layout -> A-layout).
// ---------------------------------------------------------------------------
__global__ __launch_bounds__(256) void attn(
    const unsigned short* __restrict__ q, const unsigned short* __restrict__ k,
    const unsigned short* __restrict__ vT, unsigned short* __restrict__ ctx)
{
    __shared__ unsigned short Ks[64][136];     // [kv_row][d], pad 128->136
    __shared__ unsigned short Vs[128][72];     // [d][kv_row], pad 64->72
    __shared__ unsigned short Ps[4][16][72];   // per-wave P staging

    const int qt = blockIdx.x, h = blockIdx.y, b = blockIdx.z, g = h >> 2;
    const int tid = threadIdx.x, wave = tid >> 6, lane = tid & 63;
    const int ln = lane & 15, kq = lane >> 4;

    const unsigned short* qh = q  + (size_t)(b * H_   + h) * S_ * D_;
    const unsigned short* kh = k  + (size_t)(b * HKV_ + g) * S_ * D_;
    const unsigned short* vh = vT + (size_t)(b * HKV_ + g) * D_ * S_;

    const int qrow0 = qt * 64 + wave * 16;

    short8 qf[4];
    #pragma unroll
    for (int f = 0; f < 4; f++)
        qf[f] = *(const short8*)&qh[(size_t)(qrow0 + ln) * D_ + f * 32 + kq * 8];

    floatx4 o[8];
    #pragma unroll
    for (int i = 0; i < 8; i++) { o[i][0] = 0.f; o[i][1] = 0.f; o[i][2] = 0.f; o[i][3] = 0.f; }
    float mr[4] = { -INFINITY, -INFINITY, -INFINITY, -INFINITY };
    float lr[4] = { 0.f, 0.f, 0.f, 0.f };

    for (int kt = 0; kt <= qt; kt++) {
        __syncthreads();   // previous iteration's LDS reads complete
        #pragma unroll
        for (int i = 0; i < 4; i++) {
            int id = tid + 256 * i;
            int kr = id >> 4, c  = (id & 15) * 8;
            *(uint4*)&Ks[kr][c] = *(const uint4*)&kh[(size_t)(kt * 64 + kr) * D_ + c];
            int dd = id >> 3, c2 = (id & 7) * 8;
            *(uint4*)&Vs[dd][c2] = *(const uint4*)&vh[(size_t)dd * S_ + kt * 64 + c2];
        }
        __syncthreads();

        // S = Q K^T  (16 q-rows x 64 kv-cols per wave)
        floatx4 scv[4];
        #pragma unroll
        for (int nb = 0; nb < 4; nb++) { scv[nb][0]=0.f; scv[nb][1]=0.f; scv[nb][2]=0.f; scv[nb][3]=0.f; }
        #pragma unroll
        for (int ks = 0; ks < 4; ks++) {
            #pragma unroll
            for (int nb = 0; nb < 4; nb++) {
                short8 bb = *(const short8*)&Ks[nb * 16 + ln][ks * 32 + kq * 8];
                scv[nb] = __builtin_amdgcn_mfma_f32_16x16x32_bf16(qf[ks], bb, scv[nb], 0, 0, 0);
            }
        }

        // scale + causal mask (diagonal tile only)
        if (kt == qt) {
            #pragma unroll
            for (int nb = 0; nb < 4; nb++) {
                int col = nb * 16 + ln;
                #pragma unroll
                for (int r = 0; r < 4; r++) {
                    int rowl = wave * 16 + kq * 4 + r;
                    scv[nb][r] = (col > rowl) ? -INFINITY : scv[nb][r] * SCALE;
                }
            }
        } else {
            #pragma unroll
            for (int nb = 0; nb < 4; nb++)
                #pragma unroll
                for (int r = 0; r < 4; r++) scv[nb][r] *= SCALE;
        }

        // online softmax (row stats across the 16-lane group)
        float mt[4], al[4], rs[4];
        #pragma unroll
        for (int r = 0; r < 4; r++) {
            float m = fmaxf(fmaxf(scv[0][r], scv[1][r]), fmaxf(scv[2][r], scv[3][r]));
            #pragma unroll
            for (int off = 1; off < 16; off <<= 1) m = fmaxf(m, __shfl_xor(m, off));
            mt[r] = fmaxf(mr[r], m);
            al[r] = exp2f((mr[r] - mt[r]) * LOG2E);
            mr[r] = mt[r];
            rs[r] = 0.f;
        }
        #pragma unroll
        for (int nb = 0; nb < 4; nb++) {
            #pragma unroll
            for (int r = 0; r < 4; r++) {
                float p = exp2f((scv[nb][r] - mt[r]) * LOG2E);
                rs[r] += p;
                Ps[wave][kq * 4 + r][nb * 16 + ln] = f2b(p);
            }
        }
        #pragma unroll
        for (int r = 0; r < 4; r++) {
            float t = rs[r];
            #pragma unroll
            for (int off = 1; off < 16; off <<= 1) t += __shfl_xor(t, off);
            lr[r] = lr[r] * al[r] + t;
        }
        #pragma unroll
        for (int dn = 0; dn < 8; dn++)
            #pragma unroll
            for (int r = 0; r < 4; r++) o[dn][r] *= al[r];

        __syncthreads();   // Ps writes visible

        // O += P V
        short8 pa0 = *(const short8*)&Ps[wave][ln][kq * 8];
        short8 pa1 = *(const short8*)&Ps[wave][ln][32 + kq * 8];
        #pragma unroll
        for (int dn = 0; dn < 8; dn++) {
            short8 b0 = *(const short8*)&Vs[dn * 16 + ln][kq * 8];
            o[dn] = __builtin_amdgcn_mfma_f32_16x16x32_bf16(pa0, b0, o[dn], 0, 0, 0);
            short8 b1 = *(const short8*)&Vs[dn * 16 + ln][32 + kq * 8];
            o[dn] = __builtin_amdgcn_mfma_f32_16x16x32_bf16(pa1, b1, o[dn], 0, 0, 0);
        }
    }

    // epilogue: normalize and write ctx[b*S + s][h*D + d]
    #pragma unroll
    for (int r = 0; r < 4; r++) {
        float inv = 1.0f / lr[r];
        size_t rowoff = (size_t)(b * S_ + qt * 64 + wave * 16 + kq * 4 + r) * (H_ * D_) + h * D_;
        #pragma unroll
        for (int dn = 0; dn < 8; dn++)
            ctx[rowoff + dn * 16 + ln] = f2b(o[dn][r] * inv);
    }
}

// ---------------------------------------------------------------------------
// kernel_launch — ws layout (bf16 buffers, total 88 MB):
//   WtIn  [3072][2048]  @ 0        (12 MB)
//   WtOut [2048][2048]  @ 12 MB    (8 MB)
//   x16   [4096][2048]  @ 20 MB    (16 MB)  -- dead after GEMM1; ctx aliases it
//   qkv   [4096][3072]  @ 36 MB    (24 MB)
//   q     [2][16][2048][128] @ 60 MB (16 MB)
//   k     [2][4][2048][128]  @ 76 MB (4 MB)
//   v     [2][4][2048][128]  @ 80 MB (4 MB)
//   vT    [2][4][128][2048]  @ 84 MB (4 MB)
//   ctx   [4096][2048]  @ 20 MB (aliases x16)
// ---------------------------------------------------------------------------
extern "C" void kernel_launch(void* const* d_in, const int* in_sizes, int n_in,
                              void* d_out, int out_size, void* d_ws, size_t ws_size,
                              hipStream_t stream)
{
    const float* x     = (const float*)d_in[0];
    const float* W_in  = (const float*)d_in[1];
    const float* b_in  = (const float*)d_in[2];
    const float* cw    = (const float*)d_in[3];
    const float* cb    = (const float*)d_in[4];
    const float* W_out = (const float*)d_in[5];
    const float* b_out = (const float*)d_in[6];
    float* out = (float*)d_out;
    char* ws = (char*)d_ws;

    const size_t MB = 1024 * 1024;
    unsigned short* WtIn  = (unsigned short*)(ws);
    unsigned short* WtOut = (unsigned short*)(ws + 12 * MB);
    unsigned short* x16   = (unsigned short*)(ws + 20 * MB);
    unsigned short* qkv   = (unsigned short*)(ws + 36 * MB);
    unsigned short* qa    = (unsigned short*)(ws + 60 * MB);
    unsigned short* ka    = (unsigned short*)(ws + 76 * MB);
    unsigned short* va    = (unsigned short*)(ws + 80 * MB);
    unsigned short* vTa   = (unsigned short*)(ws + 84 * MB);
    unsigned short* ctx   = (unsigned short*)(ws + 20 * MB);  // aliases x16

    dim3 tb(32, 8);
    hipLaunchKernelGGL(cvt_f32_bf16, dim3(8192), dim3(256), 0, stream, x, x16, 8388608);
    hipLaunchKernelGGL(transpose_f32_bf16, dim3(96, 64), tb, 0, stream, W_in,  WtIn,  2048, 3072);
    hipLaunchKernelGGL(transpose_f32_bf16, dim3(64, 64), tb, 0, stream, W_out, WtOut, 2048, 2048);
    hipLaunchKernelGGL(gemm_bt<0>, dim3(24, 32), dim3(256), 0, stream, x16, WtIn, b_in, (void*)qkv, 4096, 3072, 2048);
    hipLaunchKernelGGL(conv_rot, dim3(4096), dim3(256), 0, stream, qkv, cw, cb, qa, ka, va);
    hipLaunchKernelGGL(transpose_bf16, dim3(4, 64, 8), tb, 0, stream, va, vTa, 2048, 128);
    hipLaunchKernelGGL(attn, dim3(32, 16, 2), dim3(256), 0, stream, qa, ka, vTa, ctx);
    hipLaunchKernelGGL(gemm_bt<1>, dim3(16, 32), dim3(256), 0, stream, ctx, WtOut, b_out, (void*)out, 4096, 2048, 2048);
}

// Round 4
// 452.865 us; speedup vs baseline: 1.0856x; 1.0856x over previous
//
#include <hip/hip_runtime.h>
#include <hip/hip_bf16.h>

// Problem constants
#define B_    2
#define S_    2048
#define E_    2048
#define H_    16
#define HKV_  4
#define D_    128
#define QKV_  3072   // D*(H+2*HKV)

#define LOG2E  1.4426950408889634f
#define SCALE  0.08838834764831845f   // 1/sqrt(128)
#define SL     0.127517431f           // SCALE * LOG2E

typedef __attribute__((ext_vector_type(8))) short short8;   // 8 x bf16 (4 VGPRs)
typedef __attribute__((ext_vector_type(4))) float floatx4;  // MFMA 16x16 accumulator

typedef __attribute__((address_space(1))) const unsigned int gu32;
typedef __attribute__((address_space(3))) unsigned int lu32;

__device__ __forceinline__ void load_lds16(const unsigned short* g, unsigned short* l) {
    // async global->LDS, 16B/lane, dest = wave-uniform base + lane*16 (m97/m104)
    __builtin_amdgcn_global_load_lds((gu32*)g, (lu32*)l, 16, 0, 0);
}

__device__ __forceinline__ float b2f(unsigned short u) {
    union { unsigned int i; float f; } v; v.i = ((unsigned int)u) << 16; return v.f;
}
__device__ __forceinline__ unsigned short f2b(float f) {
    union { float f; unsigned int i; } v; v.f = f;
    unsigned int r = v.i + 0x7FFFu + ((v.i >> 16) & 1u);  // round-to-nearest-even
    return (unsigned short)(r >> 16);
}

// ---------------------------------------------------------------------------
// f32 -> bf16 convert (contiguous). 4 elems/thread.
// ---------------------------------------------------------------------------
__global__ __launch_bounds__(256) void cvt_f32_bf16(
    const float* __restrict__ src, unsigned short* __restrict__ dst, int n)
{
    int i = (blockIdx.x * 256 + threadIdx.x) * 4;
    if (i + 3 < n) {
        float4 v = *(const float4*)&src[i];
        ushort4 o;
        o.x = f2b(v.x); o.y = f2b(v.y); o.z = f2b(v.z); o.w = f2b(v.w);
        *(ushort4*)&dst[i] = o;
    }
}

// ---------------------------------------------------------------------------
// f32 -> bf16 transpose: src[R][C] f32 -> dst[C][R] bf16. block (32,8).
// ---------------------------------------------------------------------------
__global__ __launch_bounds__(256) void transpose_f32_bf16(
    const float* __restrict__ src, unsigned short* __restrict__ dst,
    int R, int C)
{
    __shared__ unsigned short tile[32][33];
    const int c0 = blockIdx.x * 32, r0 = blockIdx.y * 32;
    const int tx = threadIdx.x, ty = threadIdx.y;
    #pragma unroll
    for (int i = 0; i < 4; i++)
        tile[ty + 8 * i][tx] = f2b(src[(size_t)(r0 + ty + 8 * i) * C + c0 + tx]);
    __syncthreads();
    #pragma unroll
    for (int i = 0; i < 4; i++)
        dst[(size_t)(c0 + ty + 8 * i) * R + r0 + tx] = tile[tx][ty + 8 * i];
}

// ---------------------------------------------------------------------------
// bf16 -> bf16 batched transpose (for V): src[batch][R][C] -> dst[batch][C][R]
// ---------------------------------------------------------------------------
__global__ __launch_bounds__(256) void transpose_bf16(
    const unsigned short* __restrict__ src, unsigned short* __restrict__ dst,
    int R, int C)
{
    __shared__ unsigned short tile[32][33];
    const size_t boff = (size_t)blockIdx.z * R * C;
    src += boff; dst += boff;
    const int c0 = blockIdx.x * 32, r0 = blockIdx.y * 32;
    const int tx = threadIdx.x, ty = threadIdx.y;
    #pragma unroll
    for (int i = 0; i < 4; i++)
        tile[ty + 8 * i][tx] = src[(size_t)(r0 + ty + 8 * i) * C + c0 + tx];
    __syncthreads();
    #pragma unroll
    for (int i = 0; i < 4; i++)
        dst[(size_t)(c0 + ty + 8 * i) * R + r0 + tx] = tile[tx][ty + 8 * i];
}

// ---------------------------------------------------------------------------
// bf16 MFMA GEMM, B transposed: C[M][N] = A[M][K] @ Bt[N][K]^T + bias[N]
// m97 structure: 128x128 tile, BK=64, global_load_lds width-16 staging into
// unpadded [128][64] LDS (dest = wave-uniform base + lane*16).
// ---------------------------------------------------------------------------
template<int OUTF32>
__global__ __launch_bounds__(256) void gemm_bt(
    const unsigned short* __restrict__ A, const unsigned short* __restrict__ Bt,
    const float* __restrict__ bias, void* __restrict__ Cv,
    int M, int N, int K)
{
    __shared__ unsigned short As[128 * 64];
    __shared__ unsigned short Bs[128 * 64];
    const int tid = threadIdx.x;
    const int m0 = blockIdx.y * 128, n0 = blockIdx.x * 128;
    const int wave = tid >> 6, lane = tid & 63, ln = lane & 15, kq = lane >> 4;
    const int wm = (wave >> 1) * 64, wn = (wave & 1) * 64;

    floatx4 acc[4][4];
    #pragma unroll
    for (int i = 0; i < 4; i++)
        #pragma unroll
        for (int j = 0; j < 4; j++) {
            acc[i][j][0] = 0.f; acc[i][j][1] = 0.f; acc[i][j][2] = 0.f; acc[i][j][3] = 0.f;
        }

    const int lrow = lane >> 3;          // 0..7 within an 8-row chunk
    const int lcol = (lane & 7) * 8;     // 0..56

    for (int k0 = 0; k0 < K; k0 += 64) {
        __syncthreads();   // prior iteration's LDS reads complete
        #pragma unroll
        for (int c = 0; c < 4; c++) {
            int rbase = wave * 32 + c * 8;
            int row = rbase + lrow;
            load_lds16(&A [(size_t)(m0 + row) * K + k0 + lcol], &As[rbase * 64]);
            load_lds16(&Bt[(size_t)(n0 + row) * K + k0 + lcol], &Bs[rbase * 64]);
        }
        __syncthreads();   // compiler drains vmcnt before s_barrier
        #pragma unroll
        for (int ks = 0; ks < 2; ks++) {
            short8 af[4], bg[4];
            #pragma unroll
            for (int i = 0; i < 4; i++)
                af[i] = *(const short8*)&As[(wm + i * 16 + ln) * 64 + ks * 32 + kq * 8];
            #pragma unroll
            for (int j = 0; j < 4; j++)
                bg[j] = *(const short8*)&Bs[(wn + j * 16 + ln) * 64 + ks * 32 + kq * 8];
            #pragma unroll
            for (int i = 0; i < 4; i++)
                #pragma unroll
                for (int j = 0; j < 4; j++)
                    acc[i][j] = __builtin_amdgcn_mfma_f32_16x16x32_bf16(af[i], bg[j], acc[i][j], 0, 0, 0);
        }
    }

    #pragma unroll
    for (int j = 0; j < 4; j++) {
        int col = n0 + wn + j * 16 + ln;
        float bv = bias[col];
        #pragma unroll
        for (int i = 0; i < 4; i++) {
            int rowb = m0 + wm + i * 16 + kq * 4;
            #pragma unroll
            for (int r = 0; r < 4; r++) {
                float val = acc[i][j][r] + bv;
                if (OUTF32) ((float*)Cv)[(size_t)(rowb + r) * N + col] = val;
                else ((unsigned short*)Cv)[(size_t)(rowb + r) * N + col] = f2b(val);
            }
        }
    }
}

// ---------------------------------------------------------------------------
// Fused depthwise causal conv (DCONV=4) + RoPE + q/k/v split-scatter.
// ---------------------------------------------------------------------------
__device__ __forceinline__ float conv_at(
    const unsigned short* __restrict__ qb, const float* __restrict__ cw,
    const float* __restrict__ cb, int s, int c)
{
    float acc = cb[c];
    const float* w = cw + c * 4;
    #pragma unroll
    for (int t = 0; t < 4; t++) {
        int sp = s - 3 + t;
        if (sp >= 0) acc += b2f(qb[(size_t)sp * QKV_ + c]) * w[t];
    }
    return acc;
}

__global__ __launch_bounds__(256) void conv_rot(
    const unsigned short* __restrict__ qkv, const float* __restrict__ cw,
    const float* __restrict__ cb, unsigned short* __restrict__ qo,
    unsigned short* __restrict__ ko, unsigned short* __restrict__ vo)
{
    const int bs = blockIdx.x;
    const int b = bs >> 11, s = bs & 2047;
    const unsigned short* qb = qkv + (size_t)b * S_ * QKV_;

    for (int it = threadIdx.x; it < 1792; it += 256) {
        if (it < 1280) {
            const int isq = it < 1024;
            const int rel = isq ? it : it - 1024;
            const int head = rel >> 6, d = rel & 63;
            const int c1 = (isq ? head * 128 : 2048 + head * 128) + d;
            float x1 = conv_at(qb, cw, cb, s, c1);
            float x2 = conv_at(qb, cw, cb, s, c1 + 64);
            float inv = exp2f((float)d * -0.2076205059304601f);  // 10000^(-d/64)
            float ang = (float)s * inv;
            float sn, cs;
            sincosf(ang, &sn, &cs);
            float r1 = x1 * cs - x2 * sn;
            float r2 = x2 * cs + x1 * sn;
            unsigned short* dst = isq
                ? qo + ((size_t)(b * H_   + head) * S_ + s) * D_
                : ko + ((size_t)(b * HKV_ + head) * S_ + s) * D_;
            dst[d]      = f2b(r1);
            dst[d + 64] = f2b(r2);
        } else {
            const int idx = it - 1280;          // 0..511
            const int g = idx >> 7, d = idx & 127;
            float vv = conv_at(qb, cw, cb, s, 2560 + idx);
            vo[((size_t)(b * HKV_ + g) * S_ + s) * D_ + d] = f2b(vv);
        }
    }
}

// ---------------------------------------------------------------------------
// Flash attention (causal, GQA rep=4), load-balanced + S^T softmax.
// Block = (qpair, h, b); processes q-tiles qp and 31-qp (uniform 33 kv-tiles).
// S^T = K·Q^T (operand swap): lane's scv[nb][r] = S[q = qt*64+wave*16+ln]
// [kv = kt*64 + nb*16+kq*4+r]  -> softmax max/sum in-register + 2 shuffles.
// ---------------------------------------------------------------------------
__global__ __launch_bounds__(256) void attn(
    const unsigned short* __restrict__ q, const unsigned short* __restrict__ k,
    const unsigned short* __restrict__ vT, unsigned short* __restrict__ ctx)
{
    __shared__ unsigned short Ks[64][136];     // [kv_row][d], pad 128->136
    __shared__ unsigned short Vs[128][72];     // [d][kv_row], pad 64->72
    __shared__ unsigned short Ps[4][16][72];   // per-wave P staging [q][kv]

    const int qp = blockIdx.x, h = blockIdx.y, b = blockIdx.z, g = h >> 2;
    const int tid = threadIdx.x, wave = tid >> 6, lane = tid & 63;
    const int ln = lane & 15, kq = lane >> 4;

    const unsigned short* qh = q  + (size_t)(b * H_   + h) * S_ * D_;
    const unsigned short* kh = k  + (size_t)(b * HKV_ + g) * S_ * D_;
    const unsigned short* vh = vT + (size_t)(b * HKV_ + g) * D_ * S_;

    #pragma unroll
    for (int half = 0; half < 2; half++) {
        const int qt = half ? (31 - qp) : qp;
        const int qrow0 = qt * 64 + wave * 16;

        short8 qf[4];
        #pragma unroll
        for (int f = 0; f < 4; f++)
            qf[f] = *(const short8*)&qh[(size_t)(qrow0 + ln) * D_ + f * 32 + kq * 8];

        floatx4 o[8];
        #pragma unroll
        for (int i = 0; i < 8; i++) { o[i][0] = 0.f; o[i][1] = 0.f; o[i][2] = 0.f; o[i][3] = 0.f; }
        float mr = -INFINITY, lr = 0.f;

        for (int kt = 0; kt <= qt; kt++) {
            __syncthreads();   // previous tile's LDS reads complete
            #pragma unroll
            for (int i = 0; i < 4; i++) {
                int id = tid + 256 * i;
                int kr = id >> 4, c  = (id & 15) * 8;
                *(uint4*)&Ks[kr][c] = *(const uint4*)&kh[(size_t)(kt * 64 + kr) * D_ + c];
                int dd = id >> 3, c2 = (id & 7) * 8;
                *(uint4*)&Vs[dd][c2] = *(const uint4*)&vh[(size_t)dd * S_ + kt * 64 + c2];
            }
            __syncthreads();

            // S^T = K Q^T : per lane, 16 kv values for q-row (qrow0 + ln)
            floatx4 scv[4];
            #pragma unroll
            for (int nb = 0; nb < 4; nb++) { scv[nb][0]=0.f; scv[nb][1]=0.f; scv[nb][2]=0.f; scv[nb][3]=0.f; }
            #pragma unroll
            for (int ks = 0; ks < 4; ks++) {
                #pragma unroll
                for (int nb = 0; nb < 4; nb++) {
                    short8 kf = *(const short8*)&Ks[nb * 16 + ln][ks * 32 + kq * 8];
                    scv[nb] = __builtin_amdgcn_mfma_f32_16x16x32_bf16(kf, qf[ks], scv[nb], 0, 0, 0);
                }
            }

            // causal mask on diagonal tile:
            // kv_local = nb*16+kq*4+r, q_local (in 64-tile) = wave*16 + ln
            if (kt == qt) {
                const int qloc = wave * 16 + ln;
                #pragma unroll
                for (int nb = 0; nb < 4; nb++)
                    #pragma unroll
                    for (int r = 0; r < 4; r++)
                        if (nb * 16 + kq * 4 + r > qloc) scv[nb][r] = -INFINITY;
            }

            // per-lane online softmax (raw-score domain; SL folds scale+log2e)
            float mx = -INFINITY;
            #pragma unroll
            for (int nb = 0; nb < 4; nb++) {
                float a0 = fmaxf(scv[nb][0], scv[nb][1]);
                float a1 = fmaxf(scv[nb][2], scv[nb][3]);
                mx = fmaxf(mx, fmaxf(a0, a1));
            }
            mx = fmaxf(mx, __shfl_xor(mx, 16));
            mx = fmaxf(mx, __shfl_xor(mx, 32));
            float mt = fmaxf(mr, mx);
            float al = exp2f((mr - mt) * SL);
            mr = mt;

            float rs = 0.f;
            #pragma unroll
            for (int nb = 0; nb < 4; nb++) {
                #pragma unroll
                for (int r = 0; r < 4; r++) {
                    float p = exp2f((scv[nb][r] - mt) * SL);
                    rs += p;
                    Ps[wave][ln][nb * 16 + kq * 4 + r] = f2b(p);
                }
            }
            rs += __shfl_xor(rs, 16);
            rs += __shfl_xor(rs, 32);
            lr = lr * al + rs;

            // broadcast alpha to the o-layout rows (q_local = kq*4+r)
            float alr[4];
            #pragma unroll
            for (int r = 0; r < 4; r++) alr[r] = __shfl(al, kq * 4 + r);
            #pragma unroll
            for (int dn = 0; dn < 8; dn++)
                #pragma unroll
                for (int r = 0; r < 4; r++) o[dn][r] *= alr[r];

            // O += P V  (Ps is wave-private: lgkmcnt ordering suffices, no barrier)
            short8 pa0 = *(const short8*)&Ps[wave][ln][kq * 8];
            short8 pa1 = *(const short8*)&Ps[wave][ln][32 + kq * 8];
            #pragma unroll
            for (int dn = 0; dn < 8; dn++) {
                short8 b0 = *(const short8*)&Vs[dn * 16 + ln][kq * 8];
                o[dn] = __builtin_amdgcn_mfma_f32_16x16x32_bf16(pa0, b0, o[dn], 0, 0, 0);
                short8 b1 = *(const short8*)&Vs[dn * 16 + ln][32 + kq * 8];
                o[dn] = __builtin_amdgcn_mfma_f32_16x16x32_bf16(pa1, b1, o[dn], 0, 0, 0);
            }
        }

        // epilogue: broadcast 1/l to o-layout rows, write ctx[b*S+s][h*D+d]
        float lrr[4];
        #pragma unroll
        for (int r = 0; r < 4; r++) lrr[r] = 1.0f / __shfl(lr, kq * 4 + r);
        #pragma unroll
        for (int r = 0; r < 4; r++) {
            size_t rowoff = (size_t)(b * S_ + qt * 64 + wave * 16 + kq * 4 + r) * (H_ * D_) + h * D_;
            #pragma unroll
            for (int dn = 0; dn < 8; dn++)
                ctx[rowoff + dn * 16 + ln] = f2b(o[dn][r] * lrr[r]);
        }
    }
}

// ---------------------------------------------------------------------------
// kernel_launch — ws layout (bf16 buffers, total 88 MB):
//   WtIn [3072][2048] @0 (12MB) | WtOut [2048][2048] @12MB (8MB)
//   x16 [4096][2048] @20MB (16MB, ctx aliases after GEMM1)
//   qkv [4096][3072] @36MB (24MB) | q @60MB (16MB) | k @76MB (4MB)
//   v @80MB (4MB) | vT @84MB (4MB)
// ---------------------------------------------------------------------------
extern "C" void kernel_launch(void* const* d_in, const int* in_sizes, int n_in,
                              void* d_out, int out_size, void* d_ws, size_t ws_size,
                              hipStream_t stream)
{
    const float* x     = (const float*)d_in[0];
    const float* W_in  = (const float*)d_in[1];
    const float* b_in  = (const float*)d_in[2];
    const float* cw    = (const float*)d_in[3];
    const float* cb    = (const float*)d_in[4];
    const float* W_out = (const float*)d_in[5];
    const float* b_out = (const float*)d_in[6];
    float* out = (float*)d_out;
    char* ws = (char*)d_ws;

    const size_t MB = 1024 * 1024;
    unsigned short* WtIn  = (unsigned short*)(ws);
    unsigned short* WtOut = (unsigned short*)(ws + 12 * MB);
    unsigned short* x16   = (unsigned short*)(ws + 20 * MB);
    unsigned short* qkv   = (unsigned short*)(ws + 36 * MB);
    unsigned short* qa    = (unsigned short*)(ws + 60 * MB);
    unsigned short* ka    = (unsigned short*)(ws + 76 * MB);
    unsigned short* va    = (unsigned short*)(ws + 80 * MB);
    unsigned short* vTa   = (unsigned short*)(ws + 84 * MB);
    unsigned short* ctx   = (unsigned short*)(ws + 20 * MB);  // aliases x16

    dim3 tb(32, 8);
    hipLaunchKernelGGL(cvt_f32_bf16, dim3(8192), dim3(256), 0, stream, x, x16, 8388608);
    hipLaunchKernelGGL(transpose_f32_bf16, dim3(96, 64), tb, 0, stream, W_in,  WtIn,  2048, 3072);
    hipLaunchKernelGGL(transpose_f32_bf16, dim3(64, 64), tb, 0, stream, W_out, WtOut, 2048, 2048);
    hipLaunchKernelGGL(gemm_bt<0>, dim3(24, 32), dim3(256), 0, stream, x16, WtIn, b_in, (void*)qkv, 4096, 3072, 2048);
    hipLaunchKernelGGL(conv_rot, dim3(4096), dim3(256), 0, stream, qkv, cw, cb, qa, ka, va);
    hipLaunchKernelGGL(transpose_bf16, dim3(4, 64, 8), tb, 0, stream, va, vTa, 2048, 128);
    hipLaunchKernelGGL(attn, dim3(16, 16, 2), dim3(256), 0, stream, qa, ka, vTa, ctx);
    hipLaunchKernelGGL(gemm_bt<1>, dim3(16, 32), dim3(256), 0, stream, ctx, WtOut, b_out, (void*)out, 4096, 2048, 2048);
}

// Round 5
// 446.186 us; speedup vs baseline: 1.1018x; 1.0150x over previous
//
#include <hip/hip_runtime.h>
#include <hip/hip_bf16.h>

// Problem constants
#define B_    2
#define S_    2048
#define E_    2048
#define H_    16
#define HKV_  4
#define D_    128
#define QKV_  3072   // D*(H+2*HKV)

#define LOG2E  1.4426950408889634f
#define SCALE  0.08838834764831845f   // 1/sqrt(128)
#define SL     0.127517431f           // SCALE * LOG2E

typedef __attribute__((ext_vector_type(8))) short short8;   // 8 x bf16 (4 VGPRs)
typedef __attribute__((ext_vector_type(4))) float floatx4;  // MFMA 16x16 accumulator

typedef __attribute__((address_space(1))) const unsigned int gu32;
typedef __attribute__((address_space(3))) unsigned int lu32;

__device__ __forceinline__ void load_lds16(const unsigned short* g, unsigned short* l) {
    // async global->LDS, 16B/lane, dest = wave-uniform base + lane*16 (m97/m104)
    __builtin_amdgcn_global_load_lds((gu32*)g, (lu32*)l, 16, 0, 0);
}

__device__ __forceinline__ float b2f(unsigned short u) {
    union { unsigned int i; float f; } v; v.i = ((unsigned int)u) << 16; return v.f;
}
__device__ __forceinline__ unsigned short f2b(float f) {
    union { float f; unsigned int i; } v; v.f = f;
    unsigned int r = v.i + 0x7FFFu + ((v.i >> 16) & 1u);  // round-to-nearest-even
    return (unsigned short)(r >> 16);
}
__device__ __forceinline__ unsigned int fbits(float f) {
    union { float f; unsigned int i; } v; v.f = f; return v.i;
}
__device__ __forceinline__ float bits2f(unsigned int i) {
    union { unsigned int i; float f; } v; v.i = i; return v.f;
}

// ---------------------------------------------------------------------------
// f32 -> bf16 convert (contiguous). 4 elems/thread.
// ---------------------------------------------------------------------------
__global__ __launch_bounds__(256) void cvt_f32_bf16(
    const float* __restrict__ src, unsigned short* __restrict__ dst, int n)
{
    int i = (blockIdx.x * 256 + threadIdx.x) * 4;
    if (i + 3 < n) {
        float4 v = *(const float4*)&src[i];
        ushort4 o;
        o.x = f2b(v.x); o.y = f2b(v.y); o.z = f2b(v.z); o.w = f2b(v.w);
        *(ushort4*)&dst[i] = o;
    }
}

// ---------------------------------------------------------------------------
// f32 -> bf16 transpose: src[R][C] f32 -> dst[C][R] bf16. block (32,8).
// ---------------------------------------------------------------------------
__global__ __launch_bounds__(256) void transpose_f32_bf16(
    const float* __restrict__ src, unsigned short* __restrict__ dst,
    int R, int C)
{
    __shared__ unsigned short tile[32][33];
    const int c0 = blockIdx.x * 32, r0 = blockIdx.y * 32;
    const int tx = threadIdx.x, ty = threadIdx.y;
    #pragma unroll
    for (int i = 0; i < 4; i++)
        tile[ty + 8 * i][tx] = f2b(src[(size_t)(r0 + ty + 8 * i) * C + c0 + tx]);
    __syncthreads();
    #pragma unroll
    for (int i = 0; i < 4; i++)
        dst[(size_t)(c0 + ty + 8 * i) * R + r0 + tx] = tile[tx][ty + 8 * i];
}

// ---------------------------------------------------------------------------
// bf16 -> bf16 batched transpose (for V): src[batch][R][C] -> dst[batch][C][R]
// ---------------------------------------------------------------------------
__global__ __launch_bounds__(256) void transpose_bf16(
    const unsigned short* __restrict__ src, unsigned short* __restrict__ dst,
    int R, int C)
{
    __shared__ unsigned short tile[32][33];
    const size_t boff = (size_t)blockIdx.z * R * C;
    src += boff; dst += boff;
    const int c0 = blockIdx.x * 32, r0 = blockIdx.y * 32;
    const int tx = threadIdx.x, ty = threadIdx.y;
    #pragma unroll
    for (int i = 0; i < 4; i++)
        tile[ty + 8 * i][tx] = src[(size_t)(r0 + ty + 8 * i) * C + c0 + tx];
    __syncthreads();
    #pragma unroll
    for (int i = 0; i < 4; i++)
        dst[(size_t)(c0 + ty + 8 * i) * R + r0 + tx] = tile[tx][ty + 8 * i];
}

// ---------------------------------------------------------------------------
// bf16 MFMA GEMM, B transposed: C[M][N] = A[M][K] @ Bt[N][K]^T + bias[N]
// m97 structure: 128x128 tile, BK=64, global_load_lds width-16 staging into
// unpadded [128][64] LDS (dest = wave-uniform base + lane*16).
// ---------------------------------------------------------------------------
template<int OUTF32>
__global__ __launch_bounds__(256) void gemm_bt(
    const unsigned short* __restrict__ A, const unsigned short* __restrict__ Bt,
    const float* __restrict__ bias, void* __restrict__ Cv,
    int M, int N, int K)
{
    __shared__ unsigned short As[128 * 64];
    __shared__ unsigned short Bs[128 * 64];
    const int tid = threadIdx.x;
    const int m0 = blockIdx.y * 128, n0 = blockIdx.x * 128;
    const int wave = tid >> 6, lane = tid & 63, ln = lane & 15, kq = lane >> 4;
    const int wm = (wave >> 1) * 64, wn = (wave & 1) * 64;

    floatx4 acc[4][4];
    #pragma unroll
    for (int i = 0; i < 4; i++)
        #pragma unroll
        for (int j = 0; j < 4; j++) {
            acc[i][j][0] = 0.f; acc[i][j][1] = 0.f; acc[i][j][2] = 0.f; acc[i][j][3] = 0.f;
        }

    const int lrow = lane >> 3;          // 0..7 within an 8-row chunk
    const int lcol = (lane & 7) * 8;     // 0..56

    for (int k0 = 0; k0 < K; k0 += 64) {
        __syncthreads();   // prior iteration's LDS reads complete
        #pragma unroll
        for (int c = 0; c < 4; c++) {
            int rbase = wave * 32 + c * 8;
            int row = rbase + lrow;
            load_lds16(&A [(size_t)(m0 + row) * K + k0 + lcol], &As[rbase * 64]);
            load_lds16(&Bt[(size_t)(n0 + row) * K + k0 + lcol], &Bs[rbase * 64]);
        }
        __syncthreads();   // compiler drains vmcnt before s_barrier
        #pragma unroll
        for (int ks = 0; ks < 2; ks++) {
            short8 af[4], bg[4];
            #pragma unroll
            for (int i = 0; i < 4; i++)
                af[i] = *(const short8*)&As[(wm + i * 16 + ln) * 64 + ks * 32 + kq * 8];
            #pragma unroll
            for (int j = 0; j < 4; j++)
                bg[j] = *(const short8*)&Bs[(wn + j * 16 + ln) * 64 + ks * 32 + kq * 8];
            #pragma unroll
            for (int i = 0; i < 4; i++)
                #pragma unroll
                for (int j = 0; j < 4; j++)
                    acc[i][j] = __builtin_amdgcn_mfma_f32_16x16x32_bf16(af[i], bg[j], acc[i][j], 0, 0, 0);
        }
    }

    #pragma unroll
    for (int j = 0; j < 4; j++) {
        int col = n0 + wn + j * 16 + ln;
        float bv = bias[col];
        #pragma unroll
        for (int i = 0; i < 4; i++) {
            int rowb = m0 + wm + i * 16 + kq * 4;
            #pragma unroll
            for (int r = 0; r < 4; r++) {
                float val = acc[i][j][r] + bv;
                if (OUTF32) ((float*)Cv)[(size_t)(rowb + r) * N + col] = val;
                else ((unsigned short*)Cv)[(size_t)(rowb + r) * N + col] = f2b(val);
            }
        }
    }
}

// ---------------------------------------------------------------------------
// Fused depthwise causal conv (DCONV=4) + RoPE + q/k/v split-scatter.
// ---------------------------------------------------------------------------
__device__ __forceinline__ float conv_at(
    const unsigned short* __restrict__ qb, const float* __restrict__ cw,
    const float* __restrict__ cb, int s, int c)
{
    float acc = cb[c];
    const float* w = cw + c * 4;
    #pragma unroll
    for (int t = 0; t < 4; t++) {
        int sp = s - 3 + t;
        if (sp >= 0) acc += b2f(qb[(size_t)sp * QKV_ + c]) * w[t];
    }
    return acc;
}

__global__ __launch_bounds__(256) void conv_rot(
    const unsigned short* __restrict__ qkv, const float* __restrict__ cw,
    const float* __restrict__ cb, unsigned short* __restrict__ qo,
    unsigned short* __restrict__ ko, unsigned short* __restrict__ vo)
{
    const int bs = blockIdx.x;
    const int b = bs >> 11, s = bs & 2047;
    const unsigned short* qb = qkv + (size_t)b * S_ * QKV_;

    for (int it = threadIdx.x; it < 1792; it += 256) {
        if (it < 1280) {
            const int isq = it < 1024;
            const int rel = isq ? it : it - 1024;
            const int head = rel >> 6, d = rel & 63;
            const int c1 = (isq ? head * 128 : 2048 + head * 128) + d;
            float x1 = conv_at(qb, cw, cb, s, c1);
            float x2 = conv_at(qb, cw, cb, s, c1 + 64);
            float inv = exp2f((float)d * -0.2076205059304601f);  // 10000^(-d/64)
            float ang = (float)s * inv;
            float sn, cs;
            __sincosf(ang, &sn, &cs);   // fast-math: hw v_sin/v_cos, bf16-accurate
            float r1 = x1 * cs - x2 * sn;
            float r2 = x2 * cs + x1 * sn;
            unsigned short* dst = isq
                ? qo + ((size_t)(b * H_   + head) * S_ + s) * D_
                : ko + ((size_t)(b * HKV_ + head) * S_ + s) * D_;
            dst[d]      = f2b(r1);
            dst[d + 64] = f2b(r2);
        } else {
            const int idx = it - 1280;          // 0..511
            const int g = idx >> 7, d = idx & 127;
            float vv = conv_at(qb, cw, cb, s, 2560 + idx);
            vo[((size_t)(b * HKV_ + g) * S_ + s) * D_ + d] = f2b(vv);
        }
    }
}

// ---------------------------------------------------------------------------
// Flash attention (causal, GQA rep=4), load-balanced, S^T softmax,
// async global_load_lds staging into XOR-swizzled unpadded LDS tiles:
//   Ks logical [row 0..63][d-granule g 0..15], phys granule = g ^ (row&15)
//   Vs logical [d-row 0..127][kv-granule g 0..7], phys granule = g ^ (row&7)
// (granule = 8 bf16 = 16B). Swizzle applied on the GLOBAL address side so the
// DMA's lds_base+lane*16 rule holds; all frag reads land 2-way (free, m136).
// ---------------------------------------------------------------------------
__global__ __launch_bounds__(256) void attn(
    const unsigned short* __restrict__ q, const unsigned short* __restrict__ k,
    const unsigned short* __restrict__ vT, unsigned short* __restrict__ ctx)
{
    __shared__ unsigned short Ks[64 * 128];    // 16 KB, swizzled
    __shared__ unsigned short Vs[128 * 64];    // 16 KB, swizzled
    __shared__ unsigned short Ps[4][16][72];   // per-wave P staging [q][kv]

    const int qp = blockIdx.x, h = blockIdx.y, b = blockIdx.z, g = h >> 2;
    const int tid = threadIdx.x, wave = tid >> 6, lane = tid & 63;
    const int ln = lane & 15, kq = lane >> 4;

    const unsigned short* qh = q  + (size_t)(b * H_   + h) * S_ * D_;
    const unsigned short* kh = k  + (size_t)(b * HKV_ + g) * S_ * D_;
    const unsigned short* vh = vT + (size_t)(b * HKV_ + g) * D_ * S_;

    // staging geometry (per wave, 4 chunks of 1 KB each for K and V)
    const int rK = (lane >> 4);          // +4*chunk rows of K per chunk
    const int pK = lane & 15;            // phys granule within K row
    const int rV = (lane >> 3);          // +8*chunk rows of V per chunk
    const int pV = lane & 7;             // phys granule within V row

    #pragma unroll
    for (int half = 0; half < 2; half++) {
        const int qt = half ? (31 - qp) : qp;
        const int qrow0 = qt * 64 + wave * 16;

        short8 qf[4];
        #pragma unroll
        for (int f = 0; f < 4; f++)
            qf[f] = *(const short8*)&qh[(size_t)(qrow0 + ln) * D_ + f * 32 + kq * 8];

        floatx4 o[8];
        #pragma unroll
        for (int i = 0; i < 8; i++) { o[i][0] = 0.f; o[i][1] = 0.f; o[i][2] = 0.f; o[i][3] = 0.f; }
        float mr = -INFINITY, lr = 0.f;

        for (int kt = 0; kt <= qt; kt++) {
            __syncthreads();   // previous tile's LDS reads complete
            #pragma unroll
            for (int c = 0; c < 4; c++) {
                const int chunk = wave * 4 + c;        // 0..15
                // K: rows r = chunk*4 + rK, logical granule = pK ^ (r&15)
                int r  = chunk * 4 + rK;
                int gc = pK ^ (r & 15);
                load_lds16(&kh[(size_t)(kt * 64 + r) * D_ + gc * 8], &Ks[chunk * 512]);
                // V: rows rv = chunk*8 + rV, logical granule = pV ^ (rv&7)
                int rv = chunk * 8 + rV;
                int gv = pV ^ (rv & 7);
                load_lds16(&vh[(size_t)rv * S_ + kt * 64 + gv * 8], &Vs[chunk * 512]);
            }
            __syncthreads();   // vmcnt drained before barrier

            // S^T = K Q^T : per lane, 16 kv values for q-row (qrow0 + ln)
            floatx4 scv[4];
            #pragma unroll
            for (int nb = 0; nb < 4; nb++) { scv[nb][0]=0.f; scv[nb][1]=0.f; scv[nb][2]=0.f; scv[nb][3]=0.f; }
            #pragma unroll
            for (int ks = 0; ks < 4; ks++) {
                #pragma unroll
                for (int nb = 0; nb < 4; nb++) {
                    short8 kf = *(const short8*)&Ks[(nb * 16 + ln) * 128 + (((ks * 4 + kq) ^ ln) * 8)];
                    scv[nb] = __builtin_amdgcn_mfma_f32_16x16x32_bf16(kf, qf[ks], scv[nb], 0, 0, 0);
                }
            }

            // causal mask on diagonal tile:
            // kv_local = nb*16+kq*4+r, q_local (in 64-tile) = wave*16 + ln
            if (kt == qt) {
                const int qloc = wave * 16 + ln;
                #pragma unroll
                for (int nb = 0; nb < 4; nb++)
                    #pragma unroll
                    for (int r = 0; r < 4; r++)
                        if (nb * 16 + kq * 4 + r > qloc) scv[nb][r] = -INFINITY;
            }

            // per-lane online softmax (raw-score domain; SL folds scale+log2e)
            float mx = -INFINITY;
            #pragma unroll
            for (int nb = 0; nb < 4; nb++) {
                float a0 = fmaxf(scv[nb][0], scv[nb][1]);
                float a1 = fmaxf(scv[nb][2], scv[nb][3]);
                mx = fmaxf(mx, fmaxf(a0, a1));
            }
            mx = fmaxf(mx, __shfl_xor(mx, 16));
            mx = fmaxf(mx, __shfl_xor(mx, 32));
            float mt = fmaxf(mr, mx);
            float al = exp2f((mr - mt) * SL);
            mr = mt;

            // p truncated to bf16 (P>=0; denominator sums the SAME truncated
            // values so o = sum(p~ v)/sum(p~) stays an unbiased ratio);
            // pack pairs -> ds_write_b32 (8 stores vs 16, no f2b RNE chains)
            float rs = 0.f;
            #pragma unroll
            for (int nb = 0; nb < 4; nb++) {
                #pragma unroll
                for (int rr = 0; rr < 2; rr++) {
                    unsigned int u0 = fbits(exp2f((scv[nb][2 * rr]     - mt) * SL));
                    unsigned int u1 = fbits(exp2f((scv[nb][2 * rr + 1] - mt) * SL));
                    rs += bits2f(u0 & 0xFFFF0000u) + bits2f(u1 & 0xFFFF0000u);
                    *(unsigned int*)&Ps[wave][ln][nb * 16 + kq * 4 + 2 * rr] =
                        (u0 >> 16) | (u1 & 0xFFFF0000u);
                }
            }
            rs += __shfl_xor(rs, 16);
            rs += __shfl_xor(rs, 32);
            lr = lr * al + rs;

            // broadcast alpha to the o-layout rows (q_local = kq*4+r)
            float alr[4];
            #pragma unroll
            for (int r = 0; r < 4; r++) alr[r] = __shfl(al, kq * 4 + r);
            #pragma unroll
            for (int dn = 0; dn < 8; dn++)
                #pragma unroll
                for (int r = 0; r < 4; r++) o[dn][r] *= alr[r];

            // O += P V  (Ps wave-private: lgkmcnt ordering suffices, no barrier)
            short8 pa0 = *(const short8*)&Ps[wave][ln][kq * 8];
            short8 pa1 = *(const short8*)&Ps[wave][ln][32 + kq * 8];
            #pragma unroll
            for (int dn = 0; dn < 8; dn++) {
                short8 b0 = *(const short8*)&Vs[(dn * 16 + ln) * 64 + ((kq ^ (ln & 7)) * 8)];
                o[dn] = __builtin_amdgcn_mfma_f32_16x16x32_bf16(pa0, b0, o[dn], 0, 0, 0);
                short8 b1 = *(const short8*)&Vs[(dn * 16 + ln) * 64 + (((4 + kq) ^ (ln & 7)) * 8)];
                o[dn] = __builtin_amdgcn_mfma_f32_16x16x32_bf16(pa1, b1, o[dn], 0, 0, 0);
            }
        }

        // epilogue: broadcast 1/l to o-layout rows, write ctx[b*S+s][h*D+d]
        float lrr[4];
        #pragma unroll
        for (int r = 0; r < 4; r++) lrr[r] = 1.0f / __shfl(lr, kq * 4 + r);
        #pragma unroll
        for (int r = 0; r < 4; r++) {
            size_t rowoff = (size_t)(b * S_ + qt * 64 + wave * 16 + kq * 4 + r) * (H_ * D_) + h * D_;
            #pragma unroll
            for (int dn = 0; dn < 8; dn++)
                ctx[rowoff + dn * 16 + ln] = f2b(o[dn][r] * lrr[r]);
        }
    }
}

// ---------------------------------------------------------------------------
// kernel_launch — ws layout (bf16 buffers, total 88 MB):
//   WtIn [3072][2048] @0 (12MB) | WtOut [2048][2048] @12MB (8MB)
//   x16 [4096][2048] @20MB (16MB, ctx aliases after GEMM1)
//   qkv [4096][3072] @36MB (24MB) | q @60MB (16MB) | k @76MB (4MB)
//   v @80MB (4MB) | vT @84MB (4MB)
// ---------------------------------------------------------------------------
extern "C" void kernel_launch(void* const* d_in, const int* in_sizes, int n_in,
                              void* d_out, int out_size, void* d_ws, size_t ws_size,
                              hipStream_t stream)
{
    const float* x     = (const float*)d_in[0];
    const float* W_in  = (const float*)d_in[1];
    const float* b_in  = (const float*)d_in[2];
    const float* cw    = (const float*)d_in[3];
    const float* cb    = (const float*)d_in[4];
    const float* W_out = (const float*)d_in[5];
    const float* b_out = (const float*)d_in[6];
    float* out = (float*)d_out;
    char* ws = (char*)d_ws;

    const size_t MB = 1024 * 1024;
    unsigned short* WtIn  = (unsigned short*)(ws);
    unsigned short* WtOut = (unsigned short*)(ws + 12 * MB);
    unsigned short* x16   = (unsigned short*)(ws + 20 * MB);
    unsigned short* qkv   = (unsigned short*)(ws + 36 * MB);
    unsigned short* qa    = (unsigned short*)(ws + 60 * MB);
    unsigned short* ka    = (unsigned short*)(ws + 76 * MB);
    unsigned short* va    = (unsigned short*)(ws + 80 * MB);
    unsigned short* vTa   = (unsigned short*)(ws + 84 * MB);
    unsigned short* ctx   = (unsigned short*)(ws + 20 * MB);  // aliases x16

    dim3 tb(32, 8);
    hipLaunchKernelGGL(cvt_f32_bf16, dim3(8192), dim3(256), 0, stream, x, x16, 8388608);
    hipLaunchKernelGGL(transpose_f32_bf16, dim3(96, 64), tb, 0, stream, W_in,  WtIn,  2048, 3072);
    hipLaunchKernelGGL(transpose_f32_bf16, dim3(64, 64), tb, 0, stream, W_out, WtOut, 2048, 2048);
    hipLaunchKernelGGL(gemm_bt<0>, dim3(24, 32), dim3(256), 0, stream, x16, WtIn, b_in, (void*)qkv, 4096, 3072, 2048);
    hipLaunchKernelGGL(conv_rot, dim3(4096), dim3(256), 0, stream, qkv, cw, cb, qa, ka, va);
    hipLaunchKernelGGL(transpose_bf16, dim3(4, 64, 8), tb, 0, stream, va, vTa, 2048, 128);
    hipLaunchKernelGGL(attn, dim3(16, 16, 2), dim3(256), 0, stream, qa, ka, vTa, ctx);
    hipLaunchKernelGGL(gemm_bt<1>, dim3(16, 32), dim3(256), 0, stream, ctx, WtOut, b_out, (void*)out, 4096, 2048, 2048);
}

// Round 6
// 410.408 us; speedup vs baseline: 1.1979x; 1.0872x over previous
//
#include <hip/hip_runtime.h>
#include <hip/hip_bf16.h>

// Problem constants
#define B_    2
#define S_    2048
#define E_    2048
#define H_    16
#define HKV_  4
#define D_    128
#define QKV_  3072   // D*(H+2*HKV)

#define LOG2E  1.4426950408889634f
#define SCALE  0.08838834764831845f   // 1/sqrt(128)
#define SL     0.127517431f           // SCALE * LOG2E

typedef __attribute__((ext_vector_type(8))) short short8;   // 8 x bf16 (4 VGPRs)
typedef __attribute__((ext_vector_type(4))) float floatx4;  // MFMA 16x16 accumulator

typedef __attribute__((address_space(1))) const unsigned int gu32;
typedef __attribute__((address_space(3))) unsigned int lu32;

__device__ __forceinline__ void load_lds16(const unsigned short* g, unsigned short* l) {
    // async global->LDS, 16B/lane, dest = wave-uniform base + lane*16 (m97/m104)
    __builtin_amdgcn_global_load_lds((gu32*)g, (lu32*)l, 16, 0, 0);
}

__device__ __forceinline__ float b2f(unsigned short u) {
    union { unsigned int i; float f; } v; v.i = ((unsigned int)u) << 16; return v.f;
}
__device__ __forceinline__ unsigned short f2b(float f) {
    union { float f; unsigned int i; } v; v.f = f;
    unsigned int r = v.i + 0x7FFFu + ((v.i >> 16) & 1u);  // round-to-nearest-even
    return (unsigned short)(r >> 16);
}
__device__ __forceinline__ unsigned int fbits(float f) {
    union { float f; unsigned int i; } v; v.f = f; return v.i;
}
__device__ __forceinline__ float bits2f(unsigned int i) {
    union { unsigned int i; float f; } v; v.i = i; return v.f;
}

// ---------------------------------------------------------------------------
// f32 -> bf16 convert (contiguous). 4 elems/thread.
// ---------------------------------------------------------------------------
__global__ __launch_bounds__(256) void cvt_f32_bf16(
    const float* __restrict__ src, unsigned short* __restrict__ dst, int n)
{
    int i = (blockIdx.x * 256 + threadIdx.x) * 4;
    if (i + 3 < n) {
        float4 v = *(const float4*)&src[i];
        ushort4 o;
        o.x = f2b(v.x); o.y = f2b(v.y); o.z = f2b(v.z); o.w = f2b(v.w);
        *(ushort4*)&dst[i] = o;
    }
}

// ---------------------------------------------------------------------------
// f32 -> bf16 transpose: src[R][C] f32 -> dst[C][R] bf16. block (32,8).
// ---------------------------------------------------------------------------
__global__ __launch_bounds__(256) void transpose_f32_bf16(
    const float* __restrict__ src, unsigned short* __restrict__ dst,
    int R, int C)
{
    __shared__ unsigned short tile[32][33];
    const int c0 = blockIdx.x * 32, r0 = blockIdx.y * 32;
    const int tx = threadIdx.x, ty = threadIdx.y;
    #pragma unroll
    for (int i = 0; i < 4; i++)
        tile[ty + 8 * i][tx] = f2b(src[(size_t)(r0 + ty + 8 * i) * C + c0 + tx]);
    __syncthreads();
    #pragma unroll
    for (int i = 0; i < 4; i++)
        dst[(size_t)(c0 + ty + 8 * i) * R + r0 + tx] = tile[tx][ty + 8 * i];
}

// ---------------------------------------------------------------------------
// bf16 -> bf16 batched transpose (for V): src[batch][R][C] -> dst[batch][C][R]
// ---------------------------------------------------------------------------
__global__ __launch_bounds__(256) void transpose_bf16(
    const unsigned short* __restrict__ src, unsigned short* __restrict__ dst,
    int R, int C)
{
    __shared__ unsigned short tile[32][33];
    const size_t boff = (size_t)blockIdx.z * R * C;
    src += boff; dst += boff;
    const int c0 = blockIdx.x * 32, r0 = blockIdx.y * 32;
    const int tx = threadIdx.x, ty = threadIdx.y;
    #pragma unroll
    for (int i = 0; i < 4; i++)
        tile[ty + 8 * i][tx] = src[(size_t)(r0 + ty + 8 * i) * C + c0 + tx];
    __syncthreads();
    #pragma unroll
    for (int i = 0; i < 4; i++)
        dst[(size_t)(c0 + ty + 8 * i) * R + r0 + tx] = tile[tx][ty + 8 * i];
}

// ---------------------------------------------------------------------------
// bf16 MFMA GEMM, B transposed: C[M][N] = A[M][K] @ Bt[N][K]^T + bias[N]
// m97 structure: 128x128 tile, BK=64, global_load_lds width-16 staging into
// unpadded [128][64] LDS (dest = wave-uniform base + lane*16).
// ---------------------------------------------------------------------------
template<int OUTF32>
__global__ __launch_bounds__(256) void gemm_bt(
    const unsigned short* __restrict__ A, const unsigned short* __restrict__ Bt,
    const float* __restrict__ bias, void* __restrict__ Cv,
    int M, int N, int K)
{
    __shared__ unsigned short As[128 * 64];
    __shared__ unsigned short Bs[128 * 64];
    const int tid = threadIdx.x;
    const int m0 = blockIdx.y * 128, n0 = blockIdx.x * 128;
    const int wave = tid >> 6, lane = tid & 63, ln = lane & 15, kq = lane >> 4;
    const int wm = (wave >> 1) * 64, wn = (wave & 1) * 64;

    floatx4 acc[4][4];
    #pragma unroll
    for (int i = 0; i < 4; i++)
        #pragma unroll
        for (int j = 0; j < 4; j++) {
            acc[i][j][0] = 0.f; acc[i][j][1] = 0.f; acc[i][j][2] = 0.f; acc[i][j][3] = 0.f;
        }

    const int lrow = lane >> 3;          // 0..7 within an 8-row chunk
    const int lcol = (lane & 7) * 8;     // 0..56

    for (int k0 = 0; k0 < K; k0 += 64) {
        __syncthreads();   // prior iteration's LDS reads complete
        #pragma unroll
        for (int c = 0; c < 4; c++) {
            int rbase = wave * 32 + c * 8;
            int row = rbase + lrow;
            load_lds16(&A [(size_t)(m0 + row) * K + k0 + lcol], &As[rbase * 64]);
            load_lds16(&Bt[(size_t)(n0 + row) * K + k0 + lcol], &Bs[rbase * 64]);
        }
        __syncthreads();   // compiler drains vmcnt before s_barrier
        #pragma unroll
        for (int ks = 0; ks < 2; ks++) {
            short8 af[4], bg[4];
            #pragma unroll
            for (int i = 0; i < 4; i++)
                af[i] = *(const short8*)&As[(wm + i * 16 + ln) * 64 + ks * 32 + kq * 8];
            #pragma unroll
            for (int j = 0; j < 4; j++)
                bg[j] = *(const short8*)&Bs[(wn + j * 16 + ln) * 64 + ks * 32 + kq * 8];
            #pragma unroll
            for (int i = 0; i < 4; i++)
                #pragma unroll
                for (int j = 0; j < 4; j++)
                    acc[i][j] = __builtin_amdgcn_mfma_f32_16x16x32_bf16(af[i], bg[j], acc[i][j], 0, 0, 0);
        }
    }

    #pragma unroll
    for (int j = 0; j < 4; j++) {
        int col = n0 + wn + j * 16 + ln;
        float bv = bias[col];
        #pragma unroll
        for (int i = 0; i < 4; i++) {
            int rowb = m0 + wm + i * 16 + kq * 4;
            #pragma unroll
            for (int r = 0; r < 4; r++) {
                float val = acc[i][j][r] + bv;
                if (OUTF32) ((float*)Cv)[(size_t)(rowb + r) * N + col] = val;
                else ((unsigned short*)Cv)[(size_t)(rowb + r) * N + col] = f2b(val);
            }
        }
    }
}

// ---------------------------------------------------------------------------
// Fused depthwise causal conv (DCONV=4) + RoPE + q/k/v split-scatter.
// ---------------------------------------------------------------------------
__device__ __forceinline__ float conv_at(
    const unsigned short* __restrict__ qb, const float* __restrict__ cw,
    const float* __restrict__ cb, int s, int c)
{
    float acc = cb[c];
    const float* w = cw + c * 4;
    #pragma unroll
    for (int t = 0; t < 4; t++) {
        int sp = s - 3 + t;
        if (sp >= 0) acc += b2f(qb[(size_t)sp * QKV_ + c]) * w[t];
    }
    return acc;
}

__global__ __launch_bounds__(256) void conv_rot(
    const unsigned short* __restrict__ qkv, const float* __restrict__ cw,
    const float* __restrict__ cb, unsigned short* __restrict__ qo,
    unsigned short* __restrict__ ko, unsigned short* __restrict__ vo)
{
    const int bs = blockIdx.x;
    const int b = bs >> 11, s = bs & 2047;
    const unsigned short* qb = qkv + (size_t)b * S_ * QKV_;

    for (int it = threadIdx.x; it < 1792; it += 256) {
        if (it < 1280) {
            const int isq = it < 1024;
            const int rel = isq ? it : it - 1024;
            const int head = rel >> 6, d = rel & 63;
            const int c1 = (isq ? head * 128 : 2048 + head * 128) + d;
            float x1 = conv_at(qb, cw, cb, s, c1);
            float x2 = conv_at(qb, cw, cb, s, c1 + 64);
            float inv = exp2f((float)d * -0.2076205059304601f);  // 10000^(-d/64)
            float ang = (float)s * inv;
            float sn, cs;
            __sincosf(ang, &sn, &cs);   // fast-math: hw v_sin/v_cos, bf16-accurate
            float r1 = x1 * cs - x2 * sn;
            float r2 = x2 * cs + x1 * sn;
            unsigned short* dst = isq
                ? qo + ((size_t)(b * H_   + head) * S_ + s) * D_
                : ko + ((size_t)(b * HKV_ + head) * S_ + s) * D_;
            dst[d]      = f2b(r1);
            dst[d + 64] = f2b(r2);
        } else {
            const int idx = it - 1280;          // 0..511
            const int g = idx >> 7, d = idx & 127;
            float vv = conv_at(qb, cw, cb, s, 2560 + idx);
            vo[((size_t)(b * HKV_ + g) * S_ + s) * D_ + d] = f2b(vv);
        }
    }
}

// ---------------------------------------------------------------------------
// Flash attention (causal, GQA rep=4). Grid (h=16, qy=32, b=2), qt = 31-qy:
// dispatch order is monotone big-work-first (LPT) -> greedy backfill balances
// CUs without pairing; 1024 blocks = 4/CU. LDS exactly 40960 B so 4 blocks
// fit; __launch_bounds__(256,4) caps VGPR at 128 for 4 waves/SIMD.
// All LDS tiles XOR-swizzled at 16B granule: frag reads 2-way (free, m136).
// ---------------------------------------------------------------------------
__global__ __launch_bounds__(256, 4) void attn(
    const unsigned short* __restrict__ q, const unsigned short* __restrict__ k,
    const unsigned short* __restrict__ vT, unsigned short* __restrict__ ctx)
{
    __shared__ unsigned short Ks[64 * 128];    // 16 KB, swizzled
    __shared__ unsigned short Vs[128 * 64];    // 16 KB, swizzled
    __shared__ unsigned short Ps[4][16][64];   // 8 KB, per-wave, swizzled

    const int h = blockIdx.x, qt = 31 - blockIdx.y, b = blockIdx.z, g = h >> 2;
    const int tid = threadIdx.x, wave = tid >> 6, lane = tid & 63;
    const int ln = lane & 15, kq = lane >> 4;

    const unsigned short* qh = q  + (size_t)(b * H_   + h) * S_ * D_;
    const unsigned short* kh = k  + (size_t)(b * HKV_ + g) * S_ * D_;
    const unsigned short* vh = vT + (size_t)(b * HKV_ + g) * D_ * S_;

    // staging geometry (per wave, 4 chunks of 1 KB each for K and V)
    const int rK = (lane >> 4);          // +4*chunk rows of K per chunk
    const int pK = lane & 15;            // phys granule within K row
    const int rV = (lane >> 3);          // +8*chunk rows of V per chunk
    const int pV = lane & 7;             // phys granule within V row

    const int qrow0 = qt * 64 + wave * 16;

    short8 qf[4];
    #pragma unroll
    for (int f = 0; f < 4; f++)
        qf[f] = *(const short8*)&qh[(size_t)(qrow0 + ln) * D_ + f * 32 + kq * 8];

    floatx4 o[8];
    #pragma unroll
    for (int i = 0; i < 8; i++) { o[i][0] = 0.f; o[i][1] = 0.f; o[i][2] = 0.f; o[i][3] = 0.f; }
    float mr = -INFINITY, lr = 0.f;

    for (int kt = 0; kt <= qt; kt++) {
        __syncthreads();   // previous tile's LDS reads complete
        #pragma unroll
        for (int c = 0; c < 4; c++) {
            const int chunk = wave * 4 + c;        // 0..15
            // K: rows r = chunk*4 + rK, logical granule = pK ^ (r&15)
            int r  = chunk * 4 + rK;
            int gc = pK ^ (r & 15);
            load_lds16(&kh[(size_t)(kt * 64 + r) * D_ + gc * 8], &Ks[chunk * 512]);
            // V: rows rv = chunk*8 + rV, logical granule = pV ^ (rv&7)
            int rv = chunk * 8 + rV;
            int gv = pV ^ (rv & 7);
            load_lds16(&vh[(size_t)rv * S_ + kt * 64 + gv * 8], &Vs[chunk * 512]);
        }
        __syncthreads();   // vmcnt drained before barrier

        // S^T = K Q^T : per lane, 16 kv values for q-row (qrow0 + ln)
        floatx4 scv[4];
        #pragma unroll
        for (int nb = 0; nb < 4; nb++) { scv[nb][0]=0.f; scv[nb][1]=0.f; scv[nb][2]=0.f; scv[nb][3]=0.f; }
        #pragma unroll
        for (int ks = 0; ks < 4; ks++) {
            #pragma unroll
            for (int nb = 0; nb < 4; nb++) {
                short8 kf = *(const short8*)&Ks[(nb * 16 + ln) * 128 + (((ks * 4 + kq) ^ ln) * 8)];
                scv[nb] = __builtin_amdgcn_mfma_f32_16x16x32_bf16(kf, qf[ks], scv[nb], 0, 0, 0);
            }
        }

        // causal mask on diagonal tile:
        // kv_local = nb*16+kq*4+r, q_local (in 64-tile) = wave*16 + ln
        if (kt == qt) {
            const int qloc = wave * 16 + ln;
            #pragma unroll
            for (int nb = 0; nb < 4; nb++)
                #pragma unroll
                for (int r = 0; r < 4; r++)
                    if (nb * 16 + kq * 4 + r > qloc) scv[nb][r] = -INFINITY;
        }

        // per-lane online softmax (raw-score domain; SL folds scale+log2e)
        float mx = -INFINITY;
        #pragma unroll
        for (int nb = 0; nb < 4; nb++) {
            float a0 = fmaxf(scv[nb][0], scv[nb][1]);
            float a1 = fmaxf(scv[nb][2], scv[nb][3]);
            mx = fmaxf(mx, fmaxf(a0, a1));
        }
        mx = fmaxf(mx, __shfl_xor(mx, 16));
        mx = fmaxf(mx, __shfl_xor(mx, 32));
        float mt = fmaxf(mr, mx);
        float al = exp2f((mr - mt) * SL);
        mr = mt;

        // p truncated to bf16 (denominator sums the SAME truncated values);
        // paired ds_write_b32 into granule-swizzled Ps (phys gran = g^(ln&7))
        float rs = 0.f;
        #pragma unroll
        for (int nb = 0; nb < 4; nb++) {
            const int gct = 2 * nb + (kq >> 1);
            const int pbase = ((gct ^ (ln & 7)) << 3) + ((kq & 1) << 2);
            #pragma unroll
            for (int rr = 0; rr < 2; rr++) {
                unsigned int u0 = fbits(exp2f((scv[nb][2 * rr]     - mt) * SL));
                unsigned int u1 = fbits(exp2f((scv[nb][2 * rr + 1] - mt) * SL));
                rs += bits2f(u0 & 0xFFFF0000u) + bits2f(u1 & 0xFFFF0000u);
                *(unsigned int*)&Ps[wave][ln][pbase + 2 * rr] =
                    (u0 >> 16) | (u1 & 0xFFFF0000u);
            }
        }
        rs += __shfl_xor(rs, 16);
        rs += __shfl_xor(rs, 32);
        lr = lr * al + rs;

        // broadcast alpha to the o-layout rows (q_local = kq*4+r)
        float alr[4];
        #pragma unroll
        for (int r = 0; r < 4; r++) alr[r] = __shfl(al, kq * 4 + r);
        #pragma unroll
        for (int dn = 0; dn < 8; dn++)
            #pragma unroll
            for (int r = 0; r < 4; r++) o[dn][r] *= alr[r];

        // O += P V  (Ps wave-private: lgkmcnt ordering suffices, no barrier)
        short8 pa0 = *(const short8*)&Ps[wave][ln][(kq ^ (ln & 7)) << 3];
        short8 pa1 = *(const short8*)&Ps[wave][ln][((4 + kq) ^ (ln & 7)) << 3];
        #pragma unroll
        for (int dn = 0; dn < 8; dn++) {
            short8 b0 = *(const short8*)&Vs[(dn * 16 + ln) * 64 + ((kq ^ (ln & 7)) * 8)];
            o[dn] = __builtin_amdgcn_mfma_f32_16x16x32_bf16(pa0, b0, o[dn], 0, 0, 0);
            short8 b1 = *(const short8*)&Vs[(dn * 16 + ln) * 64 + (((4 + kq) ^ (ln & 7)) * 8)];
            o[dn] = __builtin_amdgcn_mfma_f32_16x16x32_bf16(pa1, b1, o[dn], 0, 0, 0);
        }
    }

    // epilogue: broadcast 1/l to o-layout rows, write ctx[b*S+s][h*D+d]
    float lrr[4];
    #pragma unroll
    for (int r = 0; r < 4; r++) lrr[r] = 1.0f / __shfl(lr, kq * 4 + r);
    #pragma unroll
    for (int r = 0; r < 4; r++) {
        size_t rowoff = (size_t)(b * S_ + qt * 64 + wave * 16 + kq * 4 + r) * (H_ * D_) + h * D_;
        #pragma unroll
        for (int dn = 0; dn < 8; dn++)
            ctx[rowoff + dn * 16 + ln] = f2b(o[dn][r] * lrr[r]);
    }
}

// ---------------------------------------------------------------------------
// kernel_launch — ws layout (bf16 buffers, total 88 MB):
//   WtIn [3072][2048] @0 (12MB) | WtOut [2048][2048] @12MB (8MB)
//   x16 [4096][2048] @20MB (16MB, ctx aliases after GEMM1)
//   qkv [4096][3072] @36MB (24MB) | q @60MB (16MB) | k @76MB (4MB)
//   v @80MB (4MB) | vT @84MB (4MB)
// ---------------------------------------------------------------------------
extern "C" void kernel_launch(void* const* d_in, const int* in_sizes, int n_in,
                              void* d_out, int out_size, void* d_ws, size_t ws_size,
                              hipStream_t stream)
{
    const float* x     = (const float*)d_in[0];
    const float* W_in  = (const float*)d_in[1];
    const float* b_in  = (const float*)d_in[2];
    const float* cw    = (const float*)d_in[3];
    const float* cb    = (const float*)d_in[4];
    const float* W_out = (const float*)d_in[5];
    const float* b_out = (const float*)d_in[6];
    float* out = (float*)d_out;
    char* ws = (char*)d_ws;

    const size_t MB = 1024 * 1024;
    unsigned short* WtIn  = (unsigned short*)(ws);
    unsigned short* WtOut = (unsigned short*)(ws + 12 * MB);
    unsigned short* x16   = (unsigned short*)(ws + 20 * MB);
    unsigned short* qkv   = (unsigned short*)(ws + 36 * MB);
    unsigned short* qa    = (unsigned short*)(ws + 60 * MB);
    unsigned short* ka    = (unsigned short*)(ws + 76 * MB);
    unsigned short* va    = (unsigned short*)(ws + 80 * MB);
    unsigned short* vTa   = (unsigned short*)(ws + 84 * MB);
    unsigned short* ctx   = (unsigned short*)(ws + 20 * MB);  // aliases x16

    dim3 tb(32, 8);
    hipLaunchKernelGGL(cvt_f32_bf16, dim3(8192), dim3(256), 0, stream, x, x16, 8388608);
    hipLaunchKernelGGL(transpose_f32_bf16, dim3(96, 64), tb, 0, stream, W_in,  WtIn,  2048, 3072);
    hipLaunchKernelGGL(transpose_f32_bf16, dim3(64, 64), tb, 0, stream, W_out, WtOut, 2048, 2048);
    hipLaunchKernelGGL(gemm_bt<0>, dim3(24, 32), dim3(256), 0, stream, x16, WtIn, b_in, (void*)qkv, 4096, 3072, 2048);
    hipLaunchKernelGGL(conv_rot, dim3(4096), dim3(256), 0, stream, qkv, cw, cb, qa, ka, va);
    hipLaunchKernelGGL(transpose_bf16, dim3(4, 64, 8), tb, 0, stream, va, vTa, 2048, 128);
    hipLaunchKernelGGL(attn, dim3(16, 32, 2), dim3(256), 0, stream, qa, ka, vTa, ctx);
    hipLaunchKernelGGL(gemm_bt<1>, dim3(16, 32), dim3(256), 0, stream, ctx, WtOut, b_out, (void*)out, 4096, 2048, 2048);
}